// Round 15
// baseline (12142.497 us; speedup 1.0000x reference)
//
#include <hip/hip_runtime.h>
#include <math.h>

#define NN 50000
#define TT 16
#define DD 128
#define MT (NN * TT)
#define NG (NN / 16)  // 3125 rnn groups
#define SCAN_B 1024
#define SCAN_NB ((NN + SCAN_B - 1) / SCAN_B)  // 49

typedef __attribute__((ext_vector_type(8))) short short8;
typedef __attribute__((ext_vector_type(4))) float f32x4;

// ---------- bf16 helpers ----------
static __device__ __forceinline__ unsigned short f2bf(float f) {
  unsigned u = __float_as_uint(f);
  u += 0x7FFFu + ((u >> 16) & 1u);  // RNE
  return (unsigned short)(u >> 16);
}
static __device__ __forceinline__ float bf_lo(unsigned v) {
  return __uint_as_float(v << 16);
}
static __device__ __forceinline__ float bf_hi(unsigned v) {
  return __uint_as_float(v & 0xffff0000u);
}

// ---------- L1: init (deg/cur/cnt) + wprep fused ----------
__global__ void k_init_prep(int* __restrict__ deg, int* __restrict__ cur,
                            int* __restrict__ cnt,
                            const float* __restrict__ Wc, const float* __restrict__ Wl,
                            const float* __restrict__ bc, const float* __restrict__ bl,
                            unsigned short* __restrict__ Wct, unsigned short* __restrict__ Wlt,
                            float* __restrict__ bsum) {
  const int b = blockIdx.x;
  if (b < 196) {
    int i = b * 256 + threadIdx.x;
    if (i < NN) { deg[i] = 1; cur[i] = 0; }
    if (i < NG) cnt[i] = 0;
  } else {
    int n = (b - 196) * 2 + (threadIdx.x >> 7);
    int k = threadIdx.x & 127;
    Wct[n * 128 + k] = f2bf(Wc[k * 128 + n]);
    Wlt[n * 128 + k] = f2bf(Wl[k * 128 + n]);
    if (n == 0) bsum[k] = bc[k] + bl[k];
  }
}

// ---------- L2: gemmx (blocks [0,gx)) fused with deg_count (blocks [gx,..)) ----------
// gemmx: Yq = int8(x@Wc), scaleN' = rowmax/127 (dinv folded later in scan3)
__global__ __launch_bounds__(256) void k_gemmx_deg(
    const float* __restrict__ X, const unsigned short* __restrict__ Wct,
    char* __restrict__ Yq, float* __restrict__ scaleN,
    const int* __restrict__ dst, int* __restrict__ deg, int E, int gx)
{
  __shared__ unsigned short sA[128 * 136];
  const int tid = threadIdx.x;
  if ((int)blockIdx.x >= gx) {
    int i = ((int)blockIdx.x - gx) * 256 + tid;
    if (i < E) atomicAdd(&deg[dst[i]], 1);
    return;
  }
  const long row0 = (long)blockIdx.x * 128;

  {
    const float4* xp = (const float4*)(X + row0 * 128);
    #pragma unroll
    for (int it = 0; it < 16; ++it) {
      float4 v = xp[it * 256 + tid];
      int q = it * 256 + tid;
      int r = q >> 5;
      int k = (q & 31) * 4;
      unsigned u0 = (unsigned)f2bf(v.x) | ((unsigned)f2bf(v.y) << 16);
      unsigned u1 = (unsigned)f2bf(v.z) | ((unsigned)f2bf(v.w) << 16);
      *(uint2*)&sA[r * 136 + k] = make_uint2(u0, u1);
    }
  }
  __syncthreads();

  const int w = tid >> 6, l = tid & 63;
  const int lr = l & 15;
  const int lk = (l >> 4) << 3;
  f32x4 acc[2][8];
  #pragma unroll
  for (int i = 0; i < 2; ++i)
    #pragma unroll
    for (int n = 0; n < 8; ++n) acc[i][n] = (f32x4){0.f, 0.f, 0.f, 0.f};

  #pragma unroll
  for (int kg = 0; kg < 4; ++kg) {
    int kb = kg * 32 + lk;
    short8 a0 = *(const short8*)&sA[(w * 32 + lr) * 136 + kb];
    short8 a1 = *(const short8*)&sA[(w * 32 + 16 + lr) * 136 + kb];
    #pragma unroll
    for (int n = 0; n < 8; ++n) {
      short8 b = *(const short8*)&Wct[(n * 16 + lr) * 128 + kb];
      acc[0][n] = __builtin_amdgcn_mfma_f32_16x16x32_bf16(b, a0, acc[0][n], 0, 0, 0);
      acc[1][n] = __builtin_amdgcn_mfma_f32_16x16x32_bf16(b, a1, acc[1][n], 0, 0, 0);
    }
  }

  const int wb = (l >> 4) * 4;
  #pragma unroll
  for (int i = 0; i < 2; ++i) {
    const long rbase = row0 + w * 32 + i * 16;
    const int node = (int)(rbase >> 4);
    const long row = rbase + lr;
    float m = 0.f;
    #pragma unroll
    for (int n = 0; n < 8; ++n)
      #pragma unroll
      for (int r = 0; r < 4; ++r) m = fmaxf(m, fabsf(acc[i][n][r]));
    #pragma unroll
    for (int mask = 1; mask < 64; mask <<= 1)
      m = fmaxf(m, __shfl_xor(m, mask, 64));
    const float f = (m > 0.f) ? 127.f / m : 0.f;
    if (l == 0) scaleN[node] = m * (1.f / 127.f);  // dinv folded in scan3
    #pragma unroll
    for (int n = 0; n < 8; ++n) {
      int q0 = (int)__builtin_rintf(acc[i][n][0] * f);
      int q1 = (int)__builtin_rintf(acc[i][n][1] * f);
      int q2 = (int)__builtin_rintf(acc[i][n][2] * f);
      int q3 = (int)__builtin_rintf(acc[i][n][3] * f);
      unsigned u = (unsigned)(q0 & 255) | ((unsigned)(q1 & 255) << 8) |
                   ((unsigned)(q2 & 255) << 16) | ((unsigned)(q3 & 255) << 24);
      *(unsigned*)(Yq + row * 128 + n * 16 + wb) = u;
    }
  }
}

// ---------- scans ----------
__global__ __launch_bounds__(SCAN_B) void k_scan1(const int* __restrict__ deg,
                                                  int* __restrict__ rowptr,
                                                  int* __restrict__ bsums,
                                                  float* __restrict__ dinv) {
  __shared__ int sm[SCAN_B];
  int tid = threadIdx.x;
  int i = blockIdx.x * SCAN_B + tid;
  int d = (i < NN) ? deg[i] : 1;
  if (i < NN) dinv[i] = rsqrtf((float)d);
  int v = d - 1;
  sm[tid] = v;
  __syncthreads();
  for (int off = 1; off < SCAN_B; off <<= 1) {
    int t = (tid >= off) ? sm[tid - off] : 0;
    __syncthreads();
    sm[tid] += t;
    __syncthreads();
  }
  if (i < NN) rowptr[i] = sm[tid] - v;
  if (tid == SCAN_B - 1) bsums[blockIdx.x] = sm[tid];
}

__global__ void k_scan2(int* __restrict__ bsums) {
  __shared__ int sm[64];
  int tid = threadIdx.x;
  int v = (tid < SCAN_NB) ? bsums[tid] : 0;
  sm[tid] = v;
  __syncthreads();
  for (int off = 1; off < 64; off <<= 1) {
    int t = (tid >= off) ? sm[tid - off] : 0;
    __syncthreads();
    sm[tid] += t;
    __syncthreads();
  }
  if (tid < SCAN_NB) bsums[tid] = sm[tid] - v;
  if (tid == 63) bsums[SCAN_NB] = sm[63];
}

// scan3 + scaleN *= dinv fold (gemmx finished in L2)
__global__ __launch_bounds__(SCAN_B) void k_scan3(int* __restrict__ rowptr,
                                                  const int* __restrict__ bsums,
                                                  float* __restrict__ scaleN,
                                                  const float* __restrict__ dinv) {
  int i = blockIdx.x * SCAN_B + threadIdx.x;
  if (i < NN) {
    rowptr[i] += bsums[blockIdx.x];
    scaleN[i] *= dinv[i];
  }
  if (i == 0) rowptr[NN] = bsums[SCAN_NB];
}

__global__ void k_fill(const int* __restrict__ src, const int* __restrict__ dst,
                       const int* __restrict__ rowptr, int* __restrict__ cur,
                       int* __restrict__ col, int e) {
  int i = blockIdx.x * blockDim.x + threadIdx.x;
  if (i < e) {
    int d = dst[i];
    int slot = atomicAdd(&cur[d], 1);
    col[rowptr[d] + slot] = src[i];
  }
}

// ---------- L7: gather (block=node) + fused group recurrence (last-block-wins) ----------
__global__ __launch_bounds__(256) void k_gather_rnn(
    const uint2* __restrict__ Yq,  // [NN][256] uint2 (8 int8)
    const float* __restrict__ scaleN,
    const int* __restrict__ col, const int* __restrict__ rowptr,
    const float* __restrict__ dinv, const float* __restrict__ bsum,
    unsigned* __restrict__ aggT,             // [TT][NN][64] u32 (2 bf16, bsum folded)
    const unsigned short* __restrict__ Wlt,  // [c][k] bf16 W_lin^T
    float* __restrict__ out,
    int* __restrict__ cnt)
{
  __shared__ unsigned sag[16 * 72];
  __shared__ unsigned short hl[16 * 144];
  __shared__ float ob[16 * 132];
  __shared__ int lastf;
  const int n = blockIdx.x;
  const int tid = threadIdx.x;

  // ===== gather phase =====
  {
    float a0 = 0, a1 = 0, a2 = 0, a3 = 0, a4 = 0, a5 = 0, a6 = 0, a7 = 0;
    {
      uint2 v = Yq[(long)n * 256 + tid];  // self loop
      float ss = scaleN[n];
      a0 = fmaf((float)(signed char)(v.x),       ss, a0);
      a1 = fmaf((float)(signed char)(v.x >> 8),  ss, a1);
      a2 = fmaf((float)(signed char)(v.x >> 16), ss, a2);
      a3 = fmaf((float)(signed char)(v.x >> 24), ss, a3);
      a4 = fmaf((float)(signed char)(v.y),       ss, a4);
      a5 = fmaf((float)(signed char)(v.y >> 8),  ss, a5);
      a6 = fmaf((float)(signed char)(v.y >> 16), ss, a6);
      a7 = fmaf((float)(signed char)(v.y >> 24), ss, a7);
    }
    int j = rowptr[n];
    const int end = rowptr[n + 1];
    for (; j + 4 <= end; j += 4) {
      int s0 = col[j], s1 = col[j + 1], s2 = col[j + 2], s3 = col[j + 3];
      float c0 = scaleN[s0], c1 = scaleN[s1], c2 = scaleN[s2], c3 = scaleN[s3];
      uint2 v0 = Yq[(long)s0 * 256 + tid];
      uint2 v1 = Yq[(long)s1 * 256 + tid];
      uint2 v2 = Yq[(long)s2 * 256 + tid];
      uint2 v3 = Yq[(long)s3 * 256 + tid];
      a0 = fmaf((float)(signed char)(v0.x),       c0, a0);
      a1 = fmaf((float)(signed char)(v0.x >> 8),  c0, a1);
      a2 = fmaf((float)(signed char)(v0.x >> 16), c0, a2);
      a3 = fmaf((float)(signed char)(v0.x >> 24), c0, a3);
      a4 = fmaf((float)(signed char)(v0.y),       c0, a4);
      a5 = fmaf((float)(signed char)(v0.y >> 8),  c0, a5);
      a6 = fmaf((float)(signed char)(v0.y >> 16), c0, a6);
      a7 = fmaf((float)(signed char)(v0.y >> 24), c0, a7);
      a0 = fmaf((float)(signed char)(v1.x),       c1, a0);
      a1 = fmaf((float)(signed char)(v1.x >> 8),  c1, a1);
      a2 = fmaf((float)(signed char)(v1.x >> 16), c1, a2);
      a3 = fmaf((float)(signed char)(v1.x >> 24), c1, a3);
      a4 = fmaf((float)(signed char)(v1.y),       c1, a4);
      a5 = fmaf((float)(signed char)(v1.y >> 8),  c1, a5);
      a6 = fmaf((float)(signed char)(v1.y >> 16), c1, a6);
      a7 = fmaf((float)(signed char)(v1.y >> 24), c1, a7);
      a0 = fmaf((float)(signed char)(v2.x),       c2, a0);
      a1 = fmaf((float)(signed char)(v2.x >> 8),  c2, a1);
      a2 = fmaf((float)(signed char)(v2.x >> 16), c2, a2);
      a3 = fmaf((float)(signed char)(v2.x >> 24), c2, a3);
      a4 = fmaf((float)(signed char)(v2.y),       c2, a4);
      a5 = fmaf((float)(signed char)(v2.y >> 8),  c2, a5);
      a6 = fmaf((float)(signed char)(v2.y >> 16), c2, a6);
      a7 = fmaf((float)(signed char)(v2.y >> 24), c2, a7);
      a0 = fmaf((float)(signed char)(v3.x),       c3, a0);
      a1 = fmaf((float)(signed char)(v3.x >> 8),  c3, a1);
      a2 = fmaf((float)(signed char)(v3.x >> 16), c3, a2);
      a3 = fmaf((float)(signed char)(v3.x >> 24), c3, a3);
      a4 = fmaf((float)(signed char)(v3.y),       c3, a4);
      a5 = fmaf((float)(signed char)(v3.y >> 8),  c3, a5);
      a6 = fmaf((float)(signed char)(v3.y >> 16), c3, a6);
      a7 = fmaf((float)(signed char)(v3.y >> 24), c3, a7);
    }
    for (; j < end; ++j) {
      int s = col[j];
      float cs = scaleN[s];
      uint2 v = Yq[(long)s * 256 + tid];
      a0 = fmaf((float)(signed char)(v.x),       cs, a0);
      a1 = fmaf((float)(signed char)(v.x >> 8),  cs, a1);
      a2 = fmaf((float)(signed char)(v.x >> 16), cs, a2);
      a3 = fmaf((float)(signed char)(v.x >> 24), cs, a3);
      a4 = fmaf((float)(signed char)(v.y),       cs, a4);
      a5 = fmaf((float)(signed char)(v.y >> 8),  cs, a5);
      a6 = fmaf((float)(signed char)(v.y >> 16), cs, a6);
      a7 = fmaf((float)(signed char)(v.y >> 24), cs, a7);
    }
    const int t = tid >> 4, dq = tid & 15;
    const float di = dinv[n];
    const float4 b0 = *(const float4*)&bsum[dq * 8];
    const float4 b1 = *(const float4*)&bsum[dq * 8 + 4];
    a0 = fmaf(a0, di, b0.x); a1 = fmaf(a1, di, b0.y);
    a2 = fmaf(a2, di, b0.z); a3 = fmaf(a3, di, b0.w);
    a4 = fmaf(a4, di, b1.x); a5 = fmaf(a5, di, b1.y);
    a6 = fmaf(a6, di, b1.z); a7 = fmaf(a7, di, b1.w);
    uint4 u;
    u.x = (unsigned)f2bf(a0) | ((unsigned)f2bf(a1) << 16);
    u.y = (unsigned)f2bf(a2) | ((unsigned)f2bf(a3) << 16);
    u.z = (unsigned)f2bf(a4) | ((unsigned)f2bf(a5) << 16);
    u.w = (unsigned)f2bf(a6) | ((unsigned)f2bf(a7) << 16);
    *(uint4*)(aggT + ((long)t * NN + n) * 64 + dq * 4) = u;  // plain store (visibility)
  }

  // ===== last-block-wins handoff =====
  __threadfence();  // device-scope release of this block's aggT stores
  __syncthreads();
  if (tid == 0) lastf = (atomicAdd(&cnt[n >> 4], 1) == 15) ? 1 : 0;
  __syncthreads();
  if (!lastf) return;
  __threadfence();  // acquire before reading other blocks' aggT

  // ===== recurrence for group g = n>>4 (16 nodes), 4-wave column split =====
  const long nbase = (long)(n >> 4) * 16;
  const int w = tid >> 6, l = tid & 63;
  const int lr = l & 15, lg = l >> 4;
  const int n0 = 2 * w, n1 = 2 * w + 1;

  uint4 gp;
  // stage agg[t=0]; prefetch t=1
  gp = ((const uint4*)(aggT + nbase * 64))[tid];
  *(uint4*)&sag[(tid >> 4) * 72 + (tid & 15) * 4] = gp;
  gp = ((const uint4*)(aggT + ((long)NN + nbase) * 64))[tid];
  __syncthreads();
  // t=0: h0 = tanh(agg0)
  #pragma unroll
  for (int jn = 0; jn < 2; ++jn) {
    const int nc = jn ? n1 : n0;
    uint2 ag = *(const uint2*)&sag[lr * 72 + nc * 8 + lg * 2];
    float o0 = tanhf(bf_lo(ag.x));
    float o1 = tanhf(bf_hi(ag.x));
    float o2 = tanhf(bf_lo(ag.y));
    float o3 = tanhf(bf_hi(ag.y));
    *(float4*)&ob[lr * 132 + nc * 16 + lg * 4] = make_float4(o0, o1, o2, o3);
    unsigned u0 = (unsigned)f2bf(o0) | ((unsigned)f2bf(o1) << 16);
    unsigned u1 = (unsigned)f2bf(o2) | ((unsigned)f2bf(o3) << 16);
    *(uint2*)&hl[lr * 144 + nc * 16 + lg * 4] = make_uint2(u0, u1);
  }
  __syncthreads();
  #pragma unroll
  for (int i = 0; i < 2; ++i) {
    int idx = i * 256 + tid;
    int r = idx >> 5, c = (idx & 31) * 4;
    float4 v = *(const float4*)&ob[r * 132 + c];
    *(float4*)(out + ((nbase + r) * TT) * 128 + c) = v;
  }

  for (int t = 1; t < TT; ++t) {
    *(uint4*)&sag[(tid >> 4) * 72 + (tid & 15) * 4] = gp;  // sag[t]
    if (t + 1 < TT)
      gp = ((const uint4*)(aggT + ((long)(t + 1) * NN + nbase) * 64))[tid];
    short8 bfr[4];
    #pragma unroll
    for (int kg = 0; kg < 4; ++kg)
      bfr[kg] = *(const short8*)&hl[lr * 144 + kg * 32 + lg * 8];
    __syncthreads();  // B1

    f32x4 acc0 = (f32x4){0.f, 0.f, 0.f, 0.f};
    f32x4 acc1 = (f32x4){0.f, 0.f, 0.f, 0.f};
    #pragma unroll
    for (int kg = 0; kg < 4; ++kg) {
      const int kb = kg * 32 + lg * 8;
      short8 b0 = *(const short8*)&Wlt[(n0 * 16 + lr) * 128 + kb];
      short8 b1 = *(const short8*)&Wlt[(n1 * 16 + lr) * 128 + kb];
      acc0 = __builtin_amdgcn_mfma_f32_16x16x32_bf16(b0, bfr[kg], acc0, 0, 0, 0);
      acc1 = __builtin_amdgcn_mfma_f32_16x16x32_bf16(b1, bfr[kg], acc1, 0, 0, 0);
    }
    #pragma unroll
    for (int jn = 0; jn < 2; ++jn) {
      const int nc = jn ? n1 : n0;
      const f32x4 ac = jn ? acc1 : acc0;
      uint2 ag = *(const uint2*)&sag[lr * 72 + nc * 8 + lg * 2];
      float o0 = tanhf(ac[0] + bf_lo(ag.x));
      float o1 = tanhf(ac[1] + bf_hi(ag.x));
      float o2 = tanhf(ac[2] + bf_lo(ag.y));
      float o3 = tanhf(ac[3] + bf_hi(ag.y));
      *(float4*)&ob[lr * 132 + nc * 16 + lg * 4] = make_float4(o0, o1, o2, o3);
      unsigned u0 = (unsigned)f2bf(o0) | ((unsigned)f2bf(o1) << 16);
      unsigned u1 = (unsigned)f2bf(o2) | ((unsigned)f2bf(o3) << 16);
      *(uint2*)&hl[lr * 144 + nc * 16 + lg * 4] = make_uint2(u0, u1);
    }
    __syncthreads();  // B2
    #pragma unroll
    for (int i = 0; i < 2; ++i) {
      int idx = i * 256 + tid;
      int r = idx >> 5, c = (idx & 31) * 4;
      float4 v = *(const float4*)&ob[r * 132 + c];
      *(float4*)(out + ((nbase + r) * TT + t) * 128 + c) = v;
    }
  }
}

extern "C" void kernel_launch(void* const* d_in, const int* in_sizes, int n_in,
                              void* d_out, int out_size, void* d_ws, size_t ws_size,
                              hipStream_t stream) {
  const float* x  = (const float*)d_in[0];
  const int*   ei = (const int*)d_in[1];
  const float* Wc = (const float*)d_in[2];
  const float* bc = (const float*)d_in[3];
  const float* Wl = (const float*)d_in[4];
  const float* bl = (const float*)d_in[5];
  float* out = (float*)d_out;
  const int E = in_sizes[1] / 2;
  const int* srcp = ei;
  const int* dstp = ei + E;

  char* w = (char*)d_ws;
  auto alloc = [&](size_t bytes) {
    char* p = w;
    w += (bytes + 255) & ~(size_t)255;
    return p;
  };
  int*            deg    = (int*)alloc(sizeof(int) * NN);
  float*          dinv   = (float*)alloc(sizeof(float) * NN);
  int*            rowptr = (int*)alloc(sizeof(int) * (NN + 1));
  int*            cur    = (int*)alloc(sizeof(int) * NN);
  int*            bsums  = (int*)alloc(sizeof(int) * (SCAN_NB + 1));
  int*            cnt    = (int*)alloc(sizeof(int) * NG);
  int*            col    = (int*)alloc(sizeof(int) * (size_t)E);
  char*           Yq     = (char*)alloc((size_t)MT * DD);                         // 102.4 MB
  float*          scaleN = (float*)alloc(sizeof(float) * NN);
  unsigned*       aggT   = (unsigned*)alloc(sizeof(unsigned) * (size_t)MT * 64);  // 204.8 MB
  float*          bsum   = (float*)alloc(sizeof(float) * DD);
  unsigned short* Wct    = (unsigned short*)alloc(sizeof(unsigned short) * 128 * 128);
  unsigned short* Wlt    = (unsigned short*)alloc(sizeof(unsigned short) * 128 * 128);

  const int degB = (E + 255) / 256;
  const int gx = MT / 128;

  // L1: init + wprep
  k_init_prep<<<260, 256, 0, stream>>>(deg, cur, cnt, Wc, Wl, bc, bl, Wct, Wlt, bsum);
  // L2: gemmx (independent of CSR) || deg_count
  k_gemmx_deg<<<gx + degB, 256, 0, stream>>>(x, Wct, Yq, scaleN, dstp, deg, E, gx);
  // L3-5: scan (+dinv, +scaleN*=dinv)
  k_scan1<<<SCAN_NB, SCAN_B, 0, stream>>>(deg, rowptr, bsums, dinv);
  k_scan2<<<1, 64, 0, stream>>>(bsums);
  k_scan3<<<SCAN_NB, SCAN_B, 0, stream>>>(rowptr, bsums, scaleN, dinv);
  // L6: CSR fill
  k_fill<<<degB, 256, 0, stream>>>(srcp, dstp, rowptr, cur, col, E);
  // L7: gather + fused group recurrence (last-block-wins)
  k_gather_rnn<<<NN, 256, 0, stream>>>((const uint2*)Yq, scaleN, col, rowptr,
                                       dinv, bsum, aggT, Wlt, out, cnt);
}

// Round 16
// 1005.006 us; speedup vs baseline: 12.0820x; 12.0820x over previous
//
#include <hip/hip_runtime.h>
#include <math.h>

#define NN 50000
#define TT 16
#define DD 128
#define MT (NN * TT)
#define SCAN_B 1024
#define SCAN_NB ((NN + SCAN_B - 1) / SCAN_B)  // 49

typedef __attribute__((ext_vector_type(8))) short short8;
typedef __attribute__((ext_vector_type(4))) float f32x4;

// ---------- bf16 helpers ----------
static __device__ __forceinline__ unsigned short f2bf(float f) {
  unsigned u = __float_as_uint(f);
  u += 0x7FFFu + ((u >> 16) & 1u);  // RNE
  return (unsigned short)(u >> 16);
}
static __device__ __forceinline__ float bf_lo(unsigned v) {
  return __uint_as_float(v << 16);
}
static __device__ __forceinline__ float bf_hi(unsigned v) {
  return __uint_as_float(v & 0xffff0000u);
}

// ---------- L1: init (deg/cur) + wprep fused ----------
__global__ void k_init_prep(int* __restrict__ deg, int* __restrict__ cur,
                            const float* __restrict__ Wc, const float* __restrict__ Wl,
                            const float* __restrict__ bc, const float* __restrict__ bl,
                            unsigned short* __restrict__ Wct, unsigned short* __restrict__ Wlt,
                            float* __restrict__ bsum) {
  const int b = blockIdx.x;
  if (b < 196) {
    int i = b * 256 + threadIdx.x;
    if (i < NN) { deg[i] = 1; cur[i] = 0; }
  } else {
    int n = (b - 196) * 2 + (threadIdx.x >> 7);
    int k = threadIdx.x & 127;
    Wct[n * 128 + k] = f2bf(Wc[k * 128 + n]);
    Wlt[n * 128 + k] = f2bf(Wl[k * 128 + n]);
    if (n == 0) bsum[k] = bc[k] + bl[k];
  }
}

// ---------- L2: gemmx (blocks [0,gx)) fused with deg_count (blocks [gx,..)) ----------
// gemmx: Yq = int8(x@Wc), scaleN' = rowmax/127 (dinv folded later in scan3)
__global__ __launch_bounds__(256) void k_gemmx_deg(
    const float* __restrict__ X, const unsigned short* __restrict__ Wct,
    char* __restrict__ Yq, float* __restrict__ scaleN,
    const int* __restrict__ dst, int* __restrict__ deg, int E, int gx)
{
  __shared__ unsigned short sA[128 * 136];
  const int tid = threadIdx.x;
  if ((int)blockIdx.x >= gx) {
    int i = ((int)blockIdx.x - gx) * 256 + tid;
    if (i < E) atomicAdd(&deg[dst[i]], 1);
    return;
  }
  const long row0 = (long)blockIdx.x * 128;

  {
    const float4* xp = (const float4*)(X + row0 * 128);
    #pragma unroll
    for (int it = 0; it < 16; ++it) {
      float4 v = xp[it * 256 + tid];
      int q = it * 256 + tid;
      int r = q >> 5;
      int k = (q & 31) * 4;
      unsigned u0 = (unsigned)f2bf(v.x) | ((unsigned)f2bf(v.y) << 16);
      unsigned u1 = (unsigned)f2bf(v.z) | ((unsigned)f2bf(v.w) << 16);
      *(uint2*)&sA[r * 136 + k] = make_uint2(u0, u1);
    }
  }
  __syncthreads();

  const int w = tid >> 6, l = tid & 63;
  const int lr = l & 15;
  const int lk = (l >> 4) << 3;
  f32x4 acc[2][8];
  #pragma unroll
  for (int i = 0; i < 2; ++i)
    #pragma unroll
    for (int n = 0; n < 8; ++n) acc[i][n] = (f32x4){0.f, 0.f, 0.f, 0.f};

  #pragma unroll
  for (int kg = 0; kg < 4; ++kg) {
    int kb = kg * 32 + lk;
    short8 a0 = *(const short8*)&sA[(w * 32 + lr) * 136 + kb];
    short8 a1 = *(const short8*)&sA[(w * 32 + 16 + lr) * 136 + kb];
    #pragma unroll
    for (int n = 0; n < 8; ++n) {
      short8 b = *(const short8*)&Wct[(n * 16 + lr) * 128 + kb];
      acc[0][n] = __builtin_amdgcn_mfma_f32_16x16x32_bf16(b, a0, acc[0][n], 0, 0, 0);
      acc[1][n] = __builtin_amdgcn_mfma_f32_16x16x32_bf16(b, a1, acc[1][n], 0, 0, 0);
    }
  }

  const int wb = (l >> 4) * 4;
  #pragma unroll
  for (int i = 0; i < 2; ++i) {
    const long rbase = row0 + w * 32 + i * 16;
    const int node = (int)(rbase >> 4);
    const long row = rbase + lr;
    float m = 0.f;
    #pragma unroll
    for (int n = 0; n < 8; ++n)
      #pragma unroll
      for (int r = 0; r < 4; ++r) m = fmaxf(m, fabsf(acc[i][n][r]));
    #pragma unroll
    for (int mask = 1; mask < 64; mask <<= 1)
      m = fmaxf(m, __shfl_xor(m, mask, 64));
    const float f = (m > 0.f) ? 127.f / m : 0.f;
    if (l == 0) scaleN[node] = m * (1.f / 127.f);  // dinv folded in scan3
    #pragma unroll
    for (int n = 0; n < 8; ++n) {
      int q0 = (int)__builtin_rintf(acc[i][n][0] * f);
      int q1 = (int)__builtin_rintf(acc[i][n][1] * f);
      int q2 = (int)__builtin_rintf(acc[i][n][2] * f);
      int q3 = (int)__builtin_rintf(acc[i][n][3] * f);
      unsigned u = (unsigned)(q0 & 255) | ((unsigned)(q1 & 255) << 8) |
                   ((unsigned)(q2 & 255) << 16) | ((unsigned)(q3 & 255) << 24);
      *(unsigned*)(Yq + row * 128 + n * 16 + wb) = u;
    }
  }
}

// ---------- scans ----------
__global__ __launch_bounds__(SCAN_B) void k_scan1(const int* __restrict__ deg,
                                                  int* __restrict__ rowptr,
                                                  int* __restrict__ bsums,
                                                  float* __restrict__ dinv) {
  __shared__ int sm[SCAN_B];
  int tid = threadIdx.x;
  int i = blockIdx.x * SCAN_B + tid;
  int d = (i < NN) ? deg[i] : 1;
  if (i < NN) dinv[i] = rsqrtf((float)d);
  int v = d - 1;
  sm[tid] = v;
  __syncthreads();
  for (int off = 1; off < SCAN_B; off <<= 1) {
    int t = (tid >= off) ? sm[tid - off] : 0;
    __syncthreads();
    sm[tid] += t;
    __syncthreads();
  }
  if (i < NN) rowptr[i] = sm[tid] - v;
  if (tid == SCAN_B - 1) bsums[blockIdx.x] = sm[tid];
}

__global__ void k_scan2(int* __restrict__ bsums) {
  __shared__ int sm[64];
  int tid = threadIdx.x;
  int v = (tid < SCAN_NB) ? bsums[tid] : 0;
  sm[tid] = v;
  __syncthreads();
  for (int off = 1; off < 64; off <<= 1) {
    int t = (tid >= off) ? sm[tid - off] : 0;
    __syncthreads();
    sm[tid] += t;
    __syncthreads();
  }
  if (tid < SCAN_NB) bsums[tid] = sm[tid] - v;
  if (tid == 63) bsums[SCAN_NB] = sm[63];
}

// scan3 + scaleN *= dinv fold (gemmx finished in L2)
__global__ __launch_bounds__(SCAN_B) void k_scan3(int* __restrict__ rowptr,
                                                  const int* __restrict__ bsums,
                                                  float* __restrict__ scaleN,
                                                  const float* __restrict__ dinv) {
  int i = blockIdx.x * SCAN_B + threadIdx.x;
  if (i < NN) {
    rowptr[i] += bsums[blockIdx.x];
    scaleN[i] *= dinv[i];
  }
  if (i == 0) rowptr[NN] = bsums[SCAN_NB];
}

__global__ void k_fill(const int* __restrict__ src, const int* __restrict__ dst,
                       const int* __restrict__ rowptr, int* __restrict__ cur,
                       int* __restrict__ col, int e) {
  int i = blockIdx.x * blockDim.x + threadIdx.x;
  if (i < e) {
    int d = dst[i];
    int slot = atomicAdd(&cur[d], 1);
    col[rowptr[d] + slot] = src[i];
  }
}

// ---------- gather: one block per node, int8 rows (2KB coalesced), bsum folded in ----------
// aggT is t-major: [TT][NN][64] u32. thread tid: t = tid>>4, d = (tid&15)*8..+8
__global__ __launch_bounds__(256) void k_gatherN(
    const uint2* __restrict__ Yq,  // [NN][256] uint2 (8 int8 each)
    const float* __restrict__ scaleN,
    const int* __restrict__ col, const int* __restrict__ rowptr,
    const float* __restrict__ dinv, const float* __restrict__ bsum,
    unsigned* __restrict__ aggT)
{
  const int n = blockIdx.x;
  const int tid = threadIdx.x;
  float a0 = 0, a1 = 0, a2 = 0, a3 = 0, a4 = 0, a5 = 0, a6 = 0, a7 = 0;
  {
    uint2 v = Yq[(long)n * 256 + tid];  // self loop
    float ss = scaleN[n];
    a0 = fmaf((float)(signed char)(v.x),       ss, a0);
    a1 = fmaf((float)(signed char)(v.x >> 8),  ss, a1);
    a2 = fmaf((float)(signed char)(v.x >> 16), ss, a2);
    a3 = fmaf((float)(signed char)(v.x >> 24), ss, a3);
    a4 = fmaf((float)(signed char)(v.y),       ss, a4);
    a5 = fmaf((float)(signed char)(v.y >> 8),  ss, a5);
    a6 = fmaf((float)(signed char)(v.y >> 16), ss, a6);
    a7 = fmaf((float)(signed char)(v.y >> 24), ss, a7);
  }
  int j = rowptr[n];
  const int end = rowptr[n + 1];
  for (; j + 4 <= end; j += 4) {
    int s0 = col[j], s1 = col[j + 1], s2 = col[j + 2], s3 = col[j + 3];
    float c0 = scaleN[s0], c1 = scaleN[s1], c2 = scaleN[s2], c3 = scaleN[s3];
    uint2 v0 = Yq[(long)s0 * 256 + tid];
    uint2 v1 = Yq[(long)s1 * 256 + tid];
    uint2 v2 = Yq[(long)s2 * 256 + tid];
    uint2 v3 = Yq[(long)s3 * 256 + tid];
    a0 = fmaf((float)(signed char)(v0.x),       c0, a0);
    a1 = fmaf((float)(signed char)(v0.x >> 8),  c0, a1);
    a2 = fmaf((float)(signed char)(v0.x >> 16), c0, a2);
    a3 = fmaf((float)(signed char)(v0.x >> 24), c0, a3);
    a4 = fmaf((float)(signed char)(v0.y),       c0, a4);
    a5 = fmaf((float)(signed char)(v0.y >> 8),  c0, a5);
    a6 = fmaf((float)(signed char)(v0.y >> 16), c0, a6);
    a7 = fmaf((float)(signed char)(v0.y >> 24), c0, a7);
    a0 = fmaf((float)(signed char)(v1.x),       c1, a0);
    a1 = fmaf((float)(signed char)(v1.x >> 8),  c1, a1);
    a2 = fmaf((float)(signed char)(v1.x >> 16), c1, a2);
    a3 = fmaf((float)(signed char)(v1.x >> 24), c1, a3);
    a4 = fmaf((float)(signed char)(v1.y),       c1, a4);
    a5 = fmaf((float)(signed char)(v1.y >> 8),  c1, a5);
    a6 = fmaf((float)(signed char)(v1.y >> 16), c1, a6);
    a7 = fmaf((float)(signed char)(v1.y >> 24), c1, a7);
    a0 = fmaf((float)(signed char)(v2.x),       c2, a0);
    a1 = fmaf((float)(signed char)(v2.x >> 8),  c2, a1);
    a2 = fmaf((float)(signed char)(v2.x >> 16), c2, a2);
    a3 = fmaf((float)(signed char)(v2.x >> 24), c2, a3);
    a4 = fmaf((float)(signed char)(v2.y),       c2, a4);
    a5 = fmaf((float)(signed char)(v2.y >> 8),  c2, a5);
    a6 = fmaf((float)(signed char)(v2.y >> 16), c2, a6);
    a7 = fmaf((float)(signed char)(v2.y >> 24), c2, a7);
    a0 = fmaf((float)(signed char)(v3.x),       c3, a0);
    a1 = fmaf((float)(signed char)(v3.x >> 8),  c3, a1);
    a2 = fmaf((float)(signed char)(v3.x >> 16), c3, a2);
    a3 = fmaf((float)(signed char)(v3.x >> 24), c3, a3);
    a4 = fmaf((float)(signed char)(v3.y),       c3, a4);
    a5 = fmaf((float)(signed char)(v3.y >> 8),  c3, a5);
    a6 = fmaf((float)(signed char)(v3.y >> 16), c3, a6);
    a7 = fmaf((float)(signed char)(v3.y >> 24), c3, a7);
  }
  for (; j < end; ++j) {
    int s = col[j];
    float cs = scaleN[s];
    uint2 v = Yq[(long)s * 256 + tid];
    a0 = fmaf((float)(signed char)(v.x),       cs, a0);
    a1 = fmaf((float)(signed char)(v.x >> 8),  cs, a1);
    a2 = fmaf((float)(signed char)(v.x >> 16), cs, a2);
    a3 = fmaf((float)(signed char)(v.x >> 24), cs, a3);
    a4 = fmaf((float)(signed char)(v.y),       cs, a4);
    a5 = fmaf((float)(signed char)(v.y >> 8),  cs, a5);
    a6 = fmaf((float)(signed char)(v.y >> 16), cs, a6);
    a7 = fmaf((float)(signed char)(v.y >> 24), cs, a7);
  }
  const int t = tid >> 4, dq = tid & 15;
  const float di = dinv[n];
  const float4 b0 = *(const float4*)&bsum[dq * 8];
  const float4 b1 = *(const float4*)&bsum[dq * 8 + 4];
  a0 = fmaf(a0, di, b0.x); a1 = fmaf(a1, di, b0.y);
  a2 = fmaf(a2, di, b0.z); a3 = fmaf(a3, di, b0.w);
  a4 = fmaf(a4, di, b1.x); a5 = fmaf(a5, di, b1.y);
  a6 = fmaf(a6, di, b1.z); a7 = fmaf(a7, di, b1.w);
  unsigned u0 = (unsigned)f2bf(a0) | ((unsigned)f2bf(a1) << 16);
  unsigned u1 = (unsigned)f2bf(a2) | ((unsigned)f2bf(a3) << 16);
  unsigned u2 = (unsigned)f2bf(a4) | ((unsigned)f2bf(a5) << 16);
  unsigned u3 = (unsigned)f2bf(a6) | ((unsigned)f2bf(a7) << 16);
  unsigned* ap = aggT + ((long)t * NN + n) * 64 + dq * 4;  // t-major
  __builtin_nontemporal_store(u0, ap);
  __builtin_nontemporal_store(u1, ap + 1);
  __builtin_nontemporal_store(u2, ap + 2);
  __builtin_nontemporal_store(u3, ap + 3);
}

// ---------- fused recurrence: all 16 t, 1 wave per 16 nodes, W in VGPRs ----------
// out writes staged via LDS -> 512B-contiguous store requests.
__global__ __launch_bounds__(64) void k_rnn(
    const unsigned* __restrict__ aggT,       // [TT][NN][64] u32 (2 bf16, bsum included)
    const unsigned short* __restrict__ Wlt,  // [c][k] bf16 W_lin^T
    float* __restrict__ out)
{
  __shared__ unsigned sag[16 * 72];        // agg tile, row pad 72 u32
  __shared__ unsigned short hl[16 * 144];  // h tile bf16, row pad 144 u16
  __shared__ float ob[16 * 132];           // out tile fp32, row pad 132
  const int l = threadIdx.x;
  const int lr = l & 15, lg = l >> 4;
  const long nbase = (long)blockIdx.x * 16;

  // hoist all W_lin^T fragments into registers (32 x short8 = 128 VGPR)
  short8 wf[4][8];
  #pragma unroll
  for (int kg = 0; kg < 4; ++kg)
    #pragma unroll
    for (int n = 0; n < 8; ++n)
      wf[kg][n] = *(const short8*)&Wlt[(n * 16 + lr) * 128 + kg * 32 + lg * 8];

  uint4 g[4];
  // stage agg[t=0] (contiguous 4KB -> LDS)
  {
    const uint4* src = (const uint4*)(aggT + nbase * 64);
    #pragma unroll
    for (int i = 0; i < 4; ++i) g[i] = src[i * 64 + l];
    #pragma unroll
    for (int i = 0; i < 4; ++i) {
      int gi = (i * 64 + l) * 4;  // u32 index in [16][64]
      *(uint4*)&sag[(gi >> 6) * 72 + (gi & 63)] = g[i];
    }
  }
  // prefetch t=1
  {
    const uint4* src = (const uint4*)(aggT + ((long)NN + nbase) * 64);
    #pragma unroll
    for (int i = 0; i < 4; ++i) g[i] = src[i * 64 + l];
  }
  __syncthreads();
  // t=0: h0 = tanh(agg0)   (bsum already folded into agg)
  #pragma unroll
  for (int n = 0; n < 8; ++n) {
    uint2 ag = *(const uint2*)&sag[lr * 72 + n * 8 + lg * 2];
    float o0 = tanhf(bf_lo(ag.x));
    float o1 = tanhf(bf_hi(ag.x));
    float o2 = tanhf(bf_lo(ag.y));
    float o3 = tanhf(bf_hi(ag.y));
    *(float4*)&ob[lr * 132 + n * 16 + lg * 4] = make_float4(o0, o1, o2, o3);
    unsigned u0 = (unsigned)f2bf(o0) | ((unsigned)f2bf(o1) << 16);
    unsigned u1 = (unsigned)f2bf(o2) | ((unsigned)f2bf(o3) << 16);
    *(uint2*)&hl[lr * 144 + n * 16 + lg * 4] = make_uint2(u0, u1);
  }
  __syncthreads();
  // coalesced out write for t=0: 2 rows per iteration, 512B contiguous per row
  #pragma unroll
  for (int i = 0; i < 8; ++i) {
    int r2 = i * 2 + (l >> 5);
    int c = (l & 31) * 4;
    float4 v = *(const float4*)&ob[r2 * 132 + c];
    *(float4*)(out + ((nbase + r2) * TT) * 128 + c) = v;
  }

  for (int t = 1; t < TT; ++t) {
    // write staged agg[t]
    #pragma unroll
    for (int i = 0; i < 4; ++i) {
      int gi = (i * 64 + l) * 4;
      *(uint4*)&sag[(gi >> 6) * 72 + (gi & 63)] = g[i];
    }
    // prefetch t+1
    if (t + 1 < TT) {
      const uint4* src = (const uint4*)(aggT + ((long)(t + 1) * NN + nbase) * 64);
      #pragma unroll
      for (int i = 0; i < 4; ++i) g[i] = src[i * 64 + l];
    }
    // B-fragments of h_{t-1}
    short8 bfr[4];
    #pragma unroll
    for (int kg = 0; kg < 4; ++kg)
      bfr[kg] = *(const short8*)&hl[lr * 144 + kg * 32 + lg * 8];
    __syncthreads();

    f32x4 acc[8];
    #pragma unroll
    for (int n = 0; n < 8; ++n) acc[n] = (f32x4){0.f, 0.f, 0.f, 0.f};
    #pragma unroll
    for (int kg = 0; kg < 4; ++kg) {
      #pragma unroll
      for (int n = 0; n < 8; ++n)
        acc[n] = __builtin_amdgcn_mfma_f32_16x16x32_bf16(wf[kg][n], bfr[kg], acc[n], 0, 0, 0);
    }
    #pragma unroll
    for (int n = 0; n < 8; ++n) {
      uint2 ag = *(const uint2*)&sag[lr * 72 + n * 8 + lg * 2];
      float o0 = tanhf(acc[n][0] + bf_lo(ag.x));
      float o1 = tanhf(acc[n][1] + bf_hi(ag.x));
      float o2 = tanhf(acc[n][2] + bf_lo(ag.y));
      float o3 = tanhf(acc[n][3] + bf_hi(ag.y));
      *(float4*)&ob[lr * 132 + n * 16 + lg * 4] = make_float4(o0, o1, o2, o3);
      unsigned u0 = (unsigned)f2bf(o0) | ((unsigned)f2bf(o1) << 16);
      unsigned u1 = (unsigned)f2bf(o2) | ((unsigned)f2bf(o3) << 16);
      *(uint2*)&hl[lr * 144 + n * 16 + lg * 4] = make_uint2(u0, u1);
    }
    __syncthreads();
    // coalesced out write: 2 rows / iter, 512B contiguous requests
    #pragma unroll
    for (int i = 0; i < 8; ++i) {
      int r2 = i * 2 + (l >> 5);
      int c = (l & 31) * 4;
      float4 v = *(const float4*)&ob[r2 * 132 + c];
      *(float4*)(out + ((nbase + r2) * TT + t) * 128 + c) = v;
    }
  }
}

extern "C" void kernel_launch(void* const* d_in, const int* in_sizes, int n_in,
                              void* d_out, int out_size, void* d_ws, size_t ws_size,
                              hipStream_t stream) {
  const float* x  = (const float*)d_in[0];
  const int*   ei = (const int*)d_in[1];
  const float* Wc = (const float*)d_in[2];
  const float* bc = (const float*)d_in[3];
  const float* Wl = (const float*)d_in[4];
  const float* bl = (const float*)d_in[5];
  float* out = (float*)d_out;
  const int E = in_sizes[1] / 2;
  const int* srcp = ei;
  const int* dstp = ei + E;

  char* w = (char*)d_ws;
  auto alloc = [&](size_t bytes) {
    char* p = w;
    w += (bytes + 255) & ~(size_t)255;
    return p;
  };
  int*            deg    = (int*)alloc(sizeof(int) * NN);
  float*          dinv   = (float*)alloc(sizeof(float) * NN);
  int*            rowptr = (int*)alloc(sizeof(int) * (NN + 1));
  int*            cur    = (int*)alloc(sizeof(int) * NN);
  int*            bsums  = (int*)alloc(sizeof(int) * (SCAN_NB + 1));
  int*            col    = (int*)alloc(sizeof(int) * (size_t)E);
  char*           Yq     = (char*)alloc((size_t)MT * DD);                         // 102.4 MB
  float*          scaleN = (float*)alloc(sizeof(float) * NN);
  unsigned*       aggT   = (unsigned*)alloc(sizeof(unsigned) * (size_t)MT * 64);  // 204.8 MB
  float*          bsum   = (float*)alloc(sizeof(float) * DD);
  unsigned short* Wct    = (unsigned short*)alloc(sizeof(unsigned short) * 128 * 128);
  unsigned short* Wlt    = (unsigned short*)alloc(sizeof(unsigned short) * 128 * 128);

  const int degB = (E + 255) / 256;
  const int gx = MT / 128;

  // L1: init + wprep
  k_init_prep<<<260, 256, 0, stream>>>(deg, cur, Wc, Wl, bc, bl, Wct, Wlt, bsum);
  // L2: gemmx (independent of CSR) || deg_count
  k_gemmx_deg<<<gx + degB, 256, 0, stream>>>(x, Wct, Yq, scaleN, dstp, deg, E, gx);
  // L3-5: scan (+dinv, +scaleN*=dinv)
  k_scan1<<<SCAN_NB, SCAN_B, 0, stream>>>(deg, rowptr, bsums, dinv);
  k_scan2<<<1, 64, 0, stream>>>(bsums);
  k_scan3<<<SCAN_NB, SCAN_B, 0, stream>>>(rowptr, bsums, scaleN, dinv);
  // L6: CSR fill
  k_fill<<<degB, 256, 0, stream>>>(srcp, dstp, rowptr, cur, col, E);
  // L7: gather (separate launch; round-15 fence fusion catastrophically regressed)
  k_gatherN<<<NN, 256, 0, stream>>>((const uint2*)Yq, scaleN, col, rowptr, dinv, bsum, aggT);
  // L8: fused recurrence
  k_rnn<<<NN / 16, 64, 0, stream>>>(aggT, Wlt, out);
}

// Round 17
// 971.992 us; speedup vs baseline: 12.4924x; 1.0340x over previous
//
#include <hip/hip_runtime.h>
#include <math.h>

#define NN 50000
#define TT 16
#define DD 128
#define MT (NN * TT)
#define SCAN_B 1024
#define SCAN_NB ((NN + SCAN_B - 1) / SCAN_B)  // 49

typedef __attribute__((ext_vector_type(8))) short short8;
typedef __attribute__((ext_vector_type(4))) float f32x4;
typedef __attribute__((ext_vector_type(4))) unsigned u32x4;

// ---------- bf16 helpers ----------
static __device__ __forceinline__ unsigned short f2bf(float f) {
  unsigned u = __float_as_uint(f);
  u += 0x7FFFu + ((u >> 16) & 1u);  // RNE
  return (unsigned short)(u >> 16);
}
static __device__ __forceinline__ float bf_lo(unsigned v) {
  return __uint_as_float(v << 16);
}
static __device__ __forceinline__ float bf_hi(unsigned v) {
  return __uint_as_float(v & 0xffff0000u);
}

// ---------- L1: init (deg/cur) + wprep fused ----------
__global__ void k_init_prep(int* __restrict__ deg, int* __restrict__ cur,
                            const float* __restrict__ Wc, const float* __restrict__ Wl,
                            const float* __restrict__ bc, const float* __restrict__ bl,
                            unsigned short* __restrict__ Wct, unsigned short* __restrict__ Wlt,
                            float* __restrict__ bsum) {
  const int b = blockIdx.x;
  if (b < 196) {
    int i = b * 256 + threadIdx.x;
    if (i < NN) { deg[i] = 1; cur[i] = 0; }
  } else {
    int n = (b - 196) * 2 + (threadIdx.x >> 7);
    int k = threadIdx.x & 127;
    Wct[n * 128 + k] = f2bf(Wc[k * 128 + n]);
    Wlt[n * 128 + k] = f2bf(Wl[k * 128 + n]);
    if (n == 0) bsum[k] = bc[k] + bl[k];
  }
}

// ---------- L2: gemmx (blocks [0,gx)) fused with deg_count (blocks [gx,..)) ----------
__global__ __launch_bounds__(256) void k_gemmx_deg(
    const float* __restrict__ X, const unsigned short* __restrict__ Wct,
    char* __restrict__ Yq, float* __restrict__ scaleN,
    const int* __restrict__ dst, int* __restrict__ deg, int E, int gx)
{
  __shared__ unsigned short sA[128 * 136];
  const int tid = threadIdx.x;
  if ((int)blockIdx.x >= gx) {
    int i = ((int)blockIdx.x - gx) * 256 + tid;
    if (i < E) atomicAdd(&deg[dst[i]], 1);
    return;
  }
  const long row0 = (long)blockIdx.x * 128;

  {
    const f32x4* xp = (const f32x4*)(X + row0 * 128);
    #pragma unroll
    for (int it = 0; it < 16; ++it) {
      f32x4 v = __builtin_nontemporal_load(xp + it * 256 + tid);  // x streamed once
      int q = it * 256 + tid;
      int r = q >> 5;
      int k = (q & 31) * 4;
      unsigned u0 = (unsigned)f2bf(v[0]) | ((unsigned)f2bf(v[1]) << 16);
      unsigned u1 = (unsigned)f2bf(v[2]) | ((unsigned)f2bf(v[3]) << 16);
      *(uint2*)&sA[r * 136 + k] = make_uint2(u0, u1);
    }
  }
  __syncthreads();

  const int w = tid >> 6, l = tid & 63;
  const int lr = l & 15;
  const int lk = (l >> 4) << 3;
  f32x4 acc[2][8];
  #pragma unroll
  for (int i = 0; i < 2; ++i)
    #pragma unroll
    for (int n = 0; n < 8; ++n) acc[i][n] = (f32x4){0.f, 0.f, 0.f, 0.f};

  #pragma unroll
  for (int kg = 0; kg < 4; ++kg) {
    int kb = kg * 32 + lk;
    short8 a0 = *(const short8*)&sA[(w * 32 + lr) * 136 + kb];
    short8 a1 = *(const short8*)&sA[(w * 32 + 16 + lr) * 136 + kb];
    #pragma unroll
    for (int n = 0; n < 8; ++n) {
      short8 b = *(const short8*)&Wct[(n * 16 + lr) * 128 + kb];
      acc[0][n] = __builtin_amdgcn_mfma_f32_16x16x32_bf16(b, a0, acc[0][n], 0, 0, 0);
      acc[1][n] = __builtin_amdgcn_mfma_f32_16x16x32_bf16(b, a1, acc[1][n], 0, 0, 0);
    }
  }

  const int wb = (l >> 4) * 4;
  #pragma unroll
  for (int i = 0; i < 2; ++i) {
    const long rbase = row0 + w * 32 + i * 16;
    const int node = (int)(rbase >> 4);
    const long row = rbase + lr;
    float m = 0.f;
    #pragma unroll
    for (int n = 0; n < 8; ++n)
      #pragma unroll
      for (int r = 0; r < 4; ++r) m = fmaxf(m, fabsf(acc[i][n][r]));
    #pragma unroll
    for (int mask = 1; mask < 64; mask <<= 1)
      m = fmaxf(m, __shfl_xor(m, mask, 64));
    const float f = (m > 0.f) ? 127.f / m : 0.f;
    if (l == 0) scaleN[node] = m * (1.f / 127.f);  // dinv folded in scan3
    #pragma unroll
    for (int n = 0; n < 8; ++n) {
      int q0 = (int)__builtin_rintf(acc[i][n][0] * f);
      int q1 = (int)__builtin_rintf(acc[i][n][1] * f);
      int q2 = (int)__builtin_rintf(acc[i][n][2] * f);
      int q3 = (int)__builtin_rintf(acc[i][n][3] * f);
      unsigned u = (unsigned)(q0 & 255) | ((unsigned)(q1 & 255) << 8) |
                   ((unsigned)(q2 & 255) << 16) | ((unsigned)(q3 & 255) << 24);
      *(unsigned*)(Yq + row * 128 + n * 16 + wb) = u;
    }
  }
}

// ---------- scans ----------
__global__ __launch_bounds__(SCAN_B) void k_scan1(const int* __restrict__ deg,
                                                  int* __restrict__ rowptr,
                                                  int* __restrict__ bsums,
                                                  float* __restrict__ dinv) {
  __shared__ int sm[SCAN_B];
  int tid = threadIdx.x;
  int i = blockIdx.x * SCAN_B + tid;
  int d = (i < NN) ? deg[i] : 1;
  if (i < NN) dinv[i] = rsqrtf((float)d);
  int v = d - 1;
  sm[tid] = v;
  __syncthreads();
  for (int off = 1; off < SCAN_B; off <<= 1) {
    int t = (tid >= off) ? sm[tid - off] : 0;
    __syncthreads();
    sm[tid] += t;
    __syncthreads();
  }
  if (i < NN) rowptr[i] = sm[tid] - v;
  if (tid == SCAN_B - 1) bsums[blockIdx.x] = sm[tid];
}

// scan3 with in-wave bsums prefix (scan2 eliminated) + scaleN *= dinv fold
__global__ __launch_bounds__(SCAN_B) void k_scan3(int* __restrict__ rowptr,
                                                  const int* __restrict__ bsums,
                                                  float* __restrict__ scaleN,
                                                  const float* __restrict__ dinv) {
  __shared__ int soff[2];
  if (threadIdx.x < 64) {
    int v = (threadIdx.x < SCAN_NB) ? bsums[threadIdx.x] : 0;
    int p = v;
    #pragma unroll
    for (int off = 1; off < 64; off <<= 1) {
      int t = __shfl_up(p, off, 64);
      if ((int)threadIdx.x >= off) p += t;
    }
    if ((int)threadIdx.x == (int)blockIdx.x) soff[0] = p - v;  // exclusive prefix
    if (threadIdx.x == 63) soff[1] = p;                        // grand total
  }
  __syncthreads();
  int i = blockIdx.x * SCAN_B + threadIdx.x;
  if (i < NN) {
    rowptr[i] += soff[0];
    scaleN[i] *= dinv[i];
  }
  if (i == 0) rowptr[NN] = soff[1];
}

__global__ void k_fill(const int* __restrict__ src, const int* __restrict__ dst,
                       const int* __restrict__ rowptr, int* __restrict__ cur,
                       int* __restrict__ col, int e) {
  int i = blockIdx.x * blockDim.x + threadIdx.x;
  if (i < e) {
    int d = dst[i];
    int slot = atomicAdd(&cur[d], 1);
    col[rowptr[d] + slot] = src[i];
  }
}

// ---------- gather: one block per node, int8 rows (2KB coalesced), bsum folded in ----------
__global__ __launch_bounds__(256) void k_gatherN(
    const uint2* __restrict__ Yq,  // [NN][256] uint2 (8 int8 each)
    const float* __restrict__ scaleN,
    const int* __restrict__ col, const int* __restrict__ rowptr,
    const float* __restrict__ dinv, const float* __restrict__ bsum,
    unsigned* __restrict__ aggT)
{
  const int n = blockIdx.x;
  const int tid = threadIdx.x;
  float a0 = 0, a1 = 0, a2 = 0, a3 = 0, a4 = 0, a5 = 0, a6 = 0, a7 = 0;
  {
    uint2 v = Yq[(long)n * 256 + tid];  // self loop
    float ss = scaleN[n];
    a0 = fmaf((float)(signed char)(v.x),       ss, a0);
    a1 = fmaf((float)(signed char)(v.x >> 8),  ss, a1);
    a2 = fmaf((float)(signed char)(v.x >> 16), ss, a2);
    a3 = fmaf((float)(signed char)(v.x >> 24), ss, a3);
    a4 = fmaf((float)(signed char)(v.y),       ss, a4);
    a5 = fmaf((float)(signed char)(v.y >> 8),  ss, a5);
    a6 = fmaf((float)(signed char)(v.y >> 16), ss, a6);
    a7 = fmaf((float)(signed char)(v.y >> 24), ss, a7);
  }
  int j = rowptr[n];
  const int end = rowptr[n + 1];
  for (; j + 4 <= end; j += 4) {
    int s0 = __builtin_nontemporal_load(col + j);      // col read once; keep L3 for Yq
    int s1 = __builtin_nontemporal_load(col + j + 1);
    int s2 = __builtin_nontemporal_load(col + j + 2);
    int s3 = __builtin_nontemporal_load(col + j + 3);
    float c0 = scaleN[s0], c1 = scaleN[s1], c2 = scaleN[s2], c3 = scaleN[s3];
    uint2 v0 = Yq[(long)s0 * 256 + tid];
    uint2 v1 = Yq[(long)s1 * 256 + tid];
    uint2 v2 = Yq[(long)s2 * 256 + tid];
    uint2 v3 = Yq[(long)s3 * 256 + tid];
    a0 = fmaf((float)(signed char)(v0.x),       c0, a0);
    a1 = fmaf((float)(signed char)(v0.x >> 8),  c0, a1);
    a2 = fmaf((float)(signed char)(v0.x >> 16), c0, a2);
    a3 = fmaf((float)(signed char)(v0.x >> 24), c0, a3);
    a4 = fmaf((float)(signed char)(v0.y),       c0, a4);
    a5 = fmaf((float)(signed char)(v0.y >> 8),  c0, a5);
    a6 = fmaf((float)(signed char)(v0.y >> 16), c0, a6);
    a7 = fmaf((float)(signed char)(v0.y >> 24), c0, a7);
    a0 = fmaf((float)(signed char)(v1.x),       c1, a0);
    a1 = fmaf((float)(signed char)(v1.x >> 8),  c1, a1);
    a2 = fmaf((float)(signed char)(v1.x >> 16), c1, a2);
    a3 = fmaf((float)(signed char)(v1.x >> 24), c1, a3);
    a4 = fmaf((float)(signed char)(v1.y),       c1, a4);
    a5 = fmaf((float)(signed char)(v1.y >> 8),  c1, a5);
    a6 = fmaf((float)(signed char)(v1.y >> 16), c1, a6);
    a7 = fmaf((float)(signed char)(v1.y >> 24), c1, a7);
    a0 = fmaf((float)(signed char)(v2.x),       c2, a0);
    a1 = fmaf((float)(signed char)(v2.x >> 8),  c2, a1);
    a2 = fmaf((float)(signed char)(v2.x >> 16), c2, a2);
    a3 = fmaf((float)(signed char)(v2.x >> 24), c2, a3);
    a4 = fmaf((float)(signed char)(v2.y),       c2, a4);
    a5 = fmaf((float)(signed char)(v2.y >> 8),  c2, a5);
    a6 = fmaf((float)(signed char)(v2.y >> 16), c2, a6);
    a7 = fmaf((float)(signed char)(v2.y >> 24), c2, a7);
    a0 = fmaf((float)(signed char)(v3.x),       c3, a0);
    a1 = fmaf((float)(signed char)(v3.x >> 8),  c3, a1);
    a2 = fmaf((float)(signed char)(v3.x >> 16), c3, a2);
    a3 = fmaf((float)(signed char)(v3.x >> 24), c3, a3);
    a4 = fmaf((float)(signed char)(v3.y),       c3, a4);
    a5 = fmaf((float)(signed char)(v3.y >> 8),  c3, a5);
    a6 = fmaf((float)(signed char)(v3.y >> 16), c3, a6);
    a7 = fmaf((float)(signed char)(v3.y >> 24), c3, a7);
  }
  for (; j < end; ++j) {
    int s = col[j];
    float cs = scaleN[s];
    uint2 v = Yq[(long)s * 256 + tid];
    a0 = fmaf((float)(signed char)(v.x),       cs, a0);
    a1 = fmaf((float)(signed char)(v.x >> 8),  cs, a1);
    a2 = fmaf((float)(signed char)(v.x >> 16), cs, a2);
    a3 = fmaf((float)(signed char)(v.x >> 24), cs, a3);
    a4 = fmaf((float)(signed char)(v.y),       cs, a4);
    a5 = fmaf((float)(signed char)(v.y >> 8),  cs, a5);
    a6 = fmaf((float)(signed char)(v.y >> 16), cs, a6);
    a7 = fmaf((float)(signed char)(v.y >> 24), cs, a7);
  }
  const int t = tid >> 4, dq = tid & 15;
  const float di = dinv[n];
  const float4 b0 = *(const float4*)&bsum[dq * 8];
  const float4 b1 = *(const float4*)&bsum[dq * 8 + 4];
  a0 = fmaf(a0, di, b0.x); a1 = fmaf(a1, di, b0.y);
  a2 = fmaf(a2, di, b0.z); a3 = fmaf(a3, di, b0.w);
  a4 = fmaf(a4, di, b1.x); a5 = fmaf(a5, di, b1.y);
  a6 = fmaf(a6, di, b1.z); a7 = fmaf(a7, di, b1.w);
  u32x4 u;
  u.x = (unsigned)f2bf(a0) | ((unsigned)f2bf(a1) << 16);
  u.y = (unsigned)f2bf(a2) | ((unsigned)f2bf(a3) << 16);
  u.z = (unsigned)f2bf(a4) | ((unsigned)f2bf(a5) << 16);
  u.w = (unsigned)f2bf(a6) | ((unsigned)f2bf(a7) << 16);
  __builtin_nontemporal_store(u, (u32x4*)(aggT + ((long)t * NN + n) * 64 + dq * 4));
}

// ---------- fused recurrence: all 16 t, 1 wave per 16 nodes, W in VGPRs ----------
__global__ __launch_bounds__(64) void k_rnn(
    const unsigned* __restrict__ aggT,       // [TT][NN][64] u32 (2 bf16, bsum included)
    const unsigned short* __restrict__ Wlt,  // [c][k] bf16 W_lin^T
    float* __restrict__ out)
{
  __shared__ unsigned sag[16 * 72];
  __shared__ unsigned short hl[16 * 144];
  __shared__ float ob[16 * 132];
  const int l = threadIdx.x;
  const int lr = l & 15, lg = l >> 4;
  const long nbase = (long)blockIdx.x * 16;

  short8 wf[4][8];
  #pragma unroll
  for (int kg = 0; kg < 4; ++kg)
    #pragma unroll
    for (int n = 0; n < 8; ++n)
      wf[kg][n] = *(const short8*)&Wlt[(n * 16 + lr) * 128 + kg * 32 + lg * 8];

  u32x4 g[4];
  {
    const u32x4* src = (const u32x4*)(aggT + nbase * 64);
    #pragma unroll
    for (int i = 0; i < 4; ++i) g[i] = __builtin_nontemporal_load(src + i * 64 + l);
    #pragma unroll
    for (int i = 0; i < 4; ++i) {
      int gi = (i * 64 + l) * 4;
      *(u32x4*)&sag[(gi >> 6) * 72 + (gi & 63)] = g[i];
    }
  }
  {
    const u32x4* src = (const u32x4*)(aggT + ((long)NN + nbase) * 64);
    #pragma unroll
    for (int i = 0; i < 4; ++i) g[i] = __builtin_nontemporal_load(src + i * 64 + l);
  }
  __syncthreads();
  #pragma unroll
  for (int n = 0; n < 8; ++n) {
    uint2 ag = *(const uint2*)&sag[lr * 72 + n * 8 + lg * 2];
    float o0 = tanhf(bf_lo(ag.x));
    float o1 = tanhf(bf_hi(ag.x));
    float o2 = tanhf(bf_lo(ag.y));
    float o3 = tanhf(bf_hi(ag.y));
    *(float4*)&ob[lr * 132 + n * 16 + lg * 4] = make_float4(o0, o1, o2, o3);
    unsigned u0 = (unsigned)f2bf(o0) | ((unsigned)f2bf(o1) << 16);
    unsigned u1 = (unsigned)f2bf(o2) | ((unsigned)f2bf(o3) << 16);
    *(uint2*)&hl[lr * 144 + n * 16 + lg * 4] = make_uint2(u0, u1);
  }
  __syncthreads();
  #pragma unroll
  for (int i = 0; i < 8; ++i) {
    int r2 = i * 2 + (l >> 5);
    int c = (l & 31) * 4;
    f32x4 v = *(const f32x4*)&ob[r2 * 132 + c];
    __builtin_nontemporal_store(v, (f32x4*)(out + ((nbase + r2) * TT) * 128 + c));
  }

  for (int t = 1; t < TT; ++t) {
    #pragma unroll
    for (int i = 0; i < 4; ++i) {
      int gi = (i * 64 + l) * 4;
      *(u32x4*)&sag[(gi >> 6) * 72 + (gi & 63)] = g[i];
    }
    if (t + 1 < TT) {
      const u32x4* src = (const u32x4*)(aggT + ((long)(t + 1) * NN + nbase) * 64);
      #pragma unroll
      for (int i = 0; i < 4; ++i) g[i] = __builtin_nontemporal_load(src + i * 64 + l);
    }
    short8 bfr[4];
    #pragma unroll
    for (int kg = 0; kg < 4; ++kg)
      bfr[kg] = *(const short8*)&hl[lr * 144 + kg * 32 + lg * 8];
    __syncthreads();

    f32x4 acc[8];
    #pragma unroll
    for (int n = 0; n < 8; ++n) acc[n] = (f32x4){0.f, 0.f, 0.f, 0.f};
    #pragma unroll
    for (int kg = 0; kg < 4; ++kg) {
      #pragma unroll
      for (int n = 0; n < 8; ++n)
        acc[n] = __builtin_amdgcn_mfma_f32_16x16x32_bf16(wf[kg][n], bfr[kg], acc[n], 0, 0, 0);
    }
    #pragma unroll
    for (int n = 0; n < 8; ++n) {
      uint2 ag = *(const uint2*)&sag[lr * 72 + n * 8 + lg * 2];
      float o0 = tanhf(acc[n][0] + bf_lo(ag.x));
      float o1 = tanhf(acc[n][1] + bf_hi(ag.x));
      float o2 = tanhf(acc[n][2] + bf_lo(ag.y));
      float o3 = tanhf(acc[n][3] + bf_hi(ag.y));
      *(float4*)&ob[lr * 132 + n * 16 + lg * 4] = make_float4(o0, o1, o2, o3);
      unsigned u0 = (unsigned)f2bf(o0) | ((unsigned)f2bf(o1) << 16);
      unsigned u1 = (unsigned)f2bf(o2) | ((unsigned)f2bf(o3) << 16);
      *(uint2*)&hl[lr * 144 + n * 16 + lg * 4] = make_uint2(u0, u1);
    }
    __syncthreads();
    #pragma unroll
    for (int i = 0; i < 8; ++i) {
      int r2 = i * 2 + (l >> 5);
      int c = (l & 31) * 4;
      f32x4 v = *(const f32x4*)&ob[r2 * 132 + c];
      __builtin_nontemporal_store(v, (f32x4*)(out + ((nbase + r2) * TT + t) * 128 + c));
    }
  }
}

extern "C" void kernel_launch(void* const* d_in, const int* in_sizes, int n_in,
                              void* d_out, int out_size, void* d_ws, size_t ws_size,
                              hipStream_t stream) {
  const float* x  = (const float*)d_in[0];
  const int*   ei = (const int*)d_in[1];
  const float* Wc = (const float*)d_in[2];
  const float* bc = (const float*)d_in[3];
  const float* Wl = (const float*)d_in[4];
  const float* bl = (const float*)d_in[5];
  float* out = (float*)d_out;
  const int E = in_sizes[1] / 2;
  const int* srcp = ei;
  const int* dstp = ei + E;

  char* w = (char*)d_ws;
  auto alloc = [&](size_t bytes) {
    char* p = w;
    w += (bytes + 255) & ~(size_t)255;
    return p;
  };
  int*            deg    = (int*)alloc(sizeof(int) * NN);
  float*          dinv   = (float*)alloc(sizeof(float) * NN);
  int*            rowptr = (int*)alloc(sizeof(int) * (NN + 1));
  int*            cur    = (int*)alloc(sizeof(int) * NN);
  int*            bsums  = (int*)alloc(sizeof(int) * (SCAN_NB + 1));
  int*            col    = (int*)alloc(sizeof(int) * (size_t)E);
  char*           Yq     = (char*)alloc((size_t)MT * DD);                         // 102.4 MB
  float*          scaleN = (float*)alloc(sizeof(float) * NN);
  unsigned*       aggT   = (unsigned*)alloc(sizeof(unsigned) * (size_t)MT * 64);  // 204.8 MB
  float*          bsum   = (float*)alloc(sizeof(float) * DD);
  unsigned short* Wct    = (unsigned short*)alloc(sizeof(unsigned short) * 128 * 128);
  unsigned short* Wlt    = (unsigned short*)alloc(sizeof(unsigned short) * 128 * 128);

  const int degB = (E + 255) / 256;
  const int gx = MT / 128;

  // L1: init + wprep
  k_init_prep<<<260, 256, 0, stream>>>(deg, cur, Wc, Wl, bc, bl, Wct, Wlt, bsum);
  // L2: gemmx || deg_count
  k_gemmx_deg<<<gx + degB, 256, 0, stream>>>(x, Wct, Yq, scaleN, dstp, deg, E, gx);
  // L3-4: scan (scan2 folded into scan3's in-wave prefix)
  k_scan1<<<SCAN_NB, SCAN_B, 0, stream>>>(deg, rowptr, bsums, dinv);
  k_scan3<<<SCAN_NB, SCAN_B, 0, stream>>>(rowptr, bsums, scaleN, dinv);
  // L5: CSR fill
  k_fill<<<degB, 256, 0, stream>>>(srcp, dstp, rowptr, cur, col, E);
  // L6: gather
  k_gatherN<<<NN, 256, 0, stream>>>((const uint2*)Yq, scaleN, col, rowptr, dinv, bsum, aggT);
  // L7: fused recurrence
  k_rnn<<<NN / 16, 64, 0, stream>>>(aggT, Wlt, out);
}